// Round 1
// baseline (586.535 us; speedup 1.0000x reference)
//
#include <hip/hip_runtime.h>
#include <stdint.h>

typedef unsigned short u16;
typedef __bf16 bf16x8 __attribute__((ext_vector_type(8)));
typedef float f32x4 __attribute__((ext_vector_type(4)));

#define B_ 2
#define S_ 2048
#define H_ 2048
#define NH_ 16
#define HD_ 128

__device__ __forceinline__ u16 f2bf(float f) {
    uint32_t u = __float_as_uint(f);
    u += 0x7fff + ((u >> 16) & 1);  // round-to-nearest-even
    return (u16)(u >> 16);
}

// ---------------- cast x (fp32 -> bf16) ----------------
__global__ __launch_bounds__(256) void cast_x_kernel(const float* __restrict__ x, u16* __restrict__ xb) {
    int i = (blockIdx.x * 256 + threadIdx.x) * 4;
    float4 v = *(const float4*)&x[i];
    ushort4 o;
    o.x = f2bf(v.x); o.y = f2bf(v.y); o.z = f2bf(v.z); o.w = f2bf(v.w);
    *(ushort4*)&xb[i] = o;
}

// ---------------- transpose + cast weights: Wt[n][k] = bf16(W[k][n]) ----------------
__global__ __launch_bounds__(256) void transpose_cast_kernel(
        const float* __restrict__ w0, const float* __restrict__ w1,
        const float* __restrict__ w2, const float* __restrict__ w3,
        u16* __restrict__ dqkv, u16* __restrict__ dwo) {
    int z = blockIdx.z;
    const float* src = (z == 0) ? w0 : (z == 1) ? w1 : (z == 2) ? w2 : w3;
    u16* dst = (z < 3) ? (dqkv + (size_t)z * H_ * H_) : dwo;
    __shared__ float tile[32][33];
    int n0 = blockIdx.x * 32, k0 = blockIdx.y * 32;
    int tx = threadIdx.x, ty = threadIdx.y;  // 32 x 8
#pragma unroll
    for (int i = 0; i < 4; i++)
        tile[ty + i * 8][tx] = src[(size_t)(k0 + ty + i * 8) * H_ + n0 + tx];
    __syncthreads();
#pragma unroll
    for (int i = 0; i < 4; i++)
        dst[(size_t)(n0 + ty + i * 8) * H_ + k0 + tx] = f2bf(tile[tx][ty + i * 8]);
}

// ---------------- GEMM: C[M,N] = A[M,K] @ Bt[N,K]^T  (bf16 in, fp32 acc) ----------------
// MODE 0: scatter bf16 output into Q/K/V [B,NH,S,HD]   (N = 6144 = 3*2048)
// MODE 1: fp32 row-major output [M,N]
#define LDT 72  // 64 + 8 pad: lane stride 144B = 4 banks mod 32 -> conflict-free-ish
template <int MODE>
__global__ __launch_bounds__(256, 2) void gemm_bt(
        const u16* __restrict__ A, const u16* __restrict__ Bt, float* __restrict__ Cout,
        u16* __restrict__ q, u16* __restrict__ k, u16* __restrict__ v,
        int M, int N, int K) {
    __shared__ u16 As[128 * LDT];
    __shared__ u16 Bs[128 * LDT];
    int tid = threadIdx.x;
    int w = tid >> 6, lane = tid & 63, quad = lane >> 4, l16 = lane & 15;
    int wm = w >> 1, wn = w & 1;
    int m0 = blockIdx.y * 128, n0 = blockIdx.x * 128;

    f32x4 acc[4][4];
#pragma unroll
    for (int mi = 0; mi < 4; mi++)
#pragma unroll
        for (int ni = 0; ni < 4; ni++)
            acc[mi][ni] = (f32x4){0.f, 0.f, 0.f, 0.f};

    for (int k0 = 0; k0 < K; k0 += 64) {
        const u16* ga = A + (size_t)m0 * K + k0;
        const u16* gb = Bt + (size_t)n0 * K + k0;
#pragma unroll
        for (int i = 0; i < 4; i++) {
            int idx = tid + i * 256;
            int row = idx >> 3, g = idx & 7;
            *(int4*)&As[row * LDT + g * 8] = *(const int4*)&ga[(size_t)row * K + g * 8];
            *(int4*)&Bs[row * LDT + g * 8] = *(const int4*)&gb[(size_t)row * K + g * 8];
        }
        __syncthreads();
#pragma unroll
        for (int ks = 0; ks < 2; ks++) {
            bf16x8 af[4], bf[4];
#pragma unroll
            for (int mi = 0; mi < 4; mi++)
                af[mi] = *(const bf16x8*)&As[(wm * 64 + mi * 16 + l16) * LDT + ks * 32 + quad * 8];
#pragma unroll
            for (int ni = 0; ni < 4; ni++)
                bf[ni] = *(const bf16x8*)&Bs[(wn * 64 + ni * 16 + l16) * LDT + ks * 32 + quad * 8];
#pragma unroll
            for (int mi = 0; mi < 4; mi++)
#pragma unroll
                for (int ni = 0; ni < 4; ni++)
                    acc[mi][ni] = __builtin_amdgcn_mfma_f32_16x16x32_bf16(af[mi], bf[ni], acc[mi][ni], 0, 0, 0);
        }
        __syncthreads();
    }

    // epilogue: D layout col = lane&15, row = quad*4 + r (m89-verified)
#pragma unroll
    for (int mi = 0; mi < 4; mi++) {
#pragma unroll
        for (int ni = 0; ni < 4; ni++) {
            int ng = n0 + wn * 64 + ni * 16 + l16;
#pragma unroll
            for (int r = 0; r < 4; r++) {
                int mg = m0 + wm * 64 + mi * 16 + quad * 4 + r;
                float val = acc[mi][ni][r];
                if (MODE == 0) {
                    int which = ng >> 11;          // 0=Q 1=K 2=V
                    int rem = ng & 2047;
                    int h = rem >> 7, d = rem & 127;
                    int b = mg >> 11, s = mg & 2047;
                    u16* base = (which == 0) ? q : (which == 1) ? k : v;
                    base[((size_t)((b * NH_ + h) * S_ + s)) * HD_ + d] = f2bf(val);
                } else {
                    Cout[(size_t)mg * N + ng] = val;
                }
            }
        }
    }
}

// ---------------- causal flash attention ----------------
// grid (S/64, NH, B), block 256 (4 waves x 16 q-rows each)
#define KLD 136  // 128 + 8 pad
#define VLD 72   // 64 + 8 pad
__global__ __launch_bounds__(256, 2) void flash_kernel(
        const u16* __restrict__ Q, const u16* __restrict__ Kb,
        const u16* __restrict__ Vb, u16* __restrict__ Ctx) {
    __shared__ u16 Ks[64 * KLD];
    __shared__ u16 Vt[128 * VLD];   // transposed: Vt[d][kv]
    __shared__ u16 Ps[64 * VLD];    // per-wave P tiles: rows w*16..w*16+15
    int tid = threadIdx.x;
    int w = tid >> 6, lane = tid & 63, quad = lane >> 4, l16 = lane & 15;
    int q0 = blockIdx.x * 64, h = blockIdx.y, b = blockIdx.z;
    size_t bh = ((size_t)b * NH_ + h) * S_ * HD_;
    const u16* Qp = Q + bh;
    const u16* Kp = Kb + bh;
    const u16* Vp = Vb + bh;
    int qw = q0 + w * 16;

    // Q fragments in registers (A-frag: A[m=lane&15][k=quad*8+j], 4 k-steps of 32)
    bf16x8 qf[4];
#pragma unroll
    for (int ks = 0; ks < 4; ks++)
        qf[ks] = *(const bf16x8*)&Qp[(size_t)(qw + l16) * HD_ + ks * 32 + quad * 8];

    float m_i[4] = {-3e38f, -3e38f, -3e38f, -3e38f};
    float l_i[4] = {0.f, 0.f, 0.f, 0.f};
    f32x4 ao[8];
#pragma unroll
    for (int dt = 0; dt < 8; dt++) ao[dt] = (f32x4){0.f, 0.f, 0.f, 0.f};

    const float scale = 0.08838834764831845f;  // 1/sqrt(128)
    int kvend = q0 + 64;  // causal

    for (int kv0 = 0; kv0 < kvend; kv0 += 64) {
        // stage K tile [64 kv][128 d] (coalesced)
#pragma unroll
        for (int i = 0; i < 4; i++) {
            int idx = tid + i * 256;
            int row = idx >> 4, g = idx & 15;
            *(int4*)&Ks[row * KLD + g * 8] = *(const int4*)&Kp[(size_t)(kv0 + row) * HD_ + g * 8];
        }
        // stage V tile transposed: Vt[d][kv]. lanes differ in kv -> conflict-free LDS writes
#pragma unroll
        for (int i = 0; i < 4; i++) {
            int idx = tid + i * 256;
            int g = idx >> 6, s = idx & 63;
            int4 pv = *(const int4*)&Vp[(size_t)(kv0 + s) * HD_ + g * 8];
            const u16* pu = (const u16*)&pv;
#pragma unroll
            for (int j = 0; j < 8; j++)
                Vt[(g * 8 + j) * VLD + s] = pu[j];
        }
        __syncthreads();

        // S = Q K^T : per wave 16 q-rows x 64 kv
        f32x4 sc[4];
#pragma unroll
        for (int nt = 0; nt < 4; nt++) {
            sc[nt] = (f32x4){0.f, 0.f, 0.f, 0.f};
#pragma unroll
            for (int ks = 0; ks < 4; ks++) {
                bf16x8 kf = *(const bf16x8*)&Ks[(nt * 16 + l16) * KLD + ks * 32 + quad * 8];
                sc[nt] = __builtin_amdgcn_mfma_f32_16x16x32_bf16(qf[ks], kf, sc[nt], 0, 0, 0);
            }
        }

        // mask + scale + online softmax (rows = quad*4+r, cols = l16 within quad)
#pragma unroll
        for (int r = 0; r < 4; r++) {
            int qg = qw + quad * 4 + r;
            float mx = -3e38f;
#pragma unroll
            for (int nt = 0; nt < 4; nt++) {
                int kvg = kv0 + nt * 16 + l16;
                float vv = sc[nt][r] * scale;
                if (kvg > qg) vv = -3e38f;
                sc[nt][r] = vv;
                mx = fmaxf(mx, vv);
            }
            mx = fmaxf(mx, __shfl_xor(mx, 1));
            mx = fmaxf(mx, __shfl_xor(mx, 2));
            mx = fmaxf(mx, __shfl_xor(mx, 4));
            mx = fmaxf(mx, __shfl_xor(mx, 8));
            float mn = fmaxf(m_i[r], mx);
            float alpha = __expf(m_i[r] - mn);
            float rs = 0.f;
#pragma unroll
            for (int nt = 0; nt < 4; nt++) {
                float p = __expf(sc[nt][r] - mn);
                sc[nt][r] = p;
                rs += p;
            }
            rs += __shfl_xor(rs, 1);
            rs += __shfl_xor(rs, 2);
            rs += __shfl_xor(rs, 4);
            rs += __shfl_xor(rs, 8);
            l_i[r] = l_i[r] * alpha + rs;
            m_i[r] = mn;
#pragma unroll
            for (int dt = 0; dt < 8; dt++) ao[dt][r] *= alpha;
            // P: C-layout -> LDS (per-wave region; same-wave DS ops are in-order)
#pragma unroll
            for (int nt = 0; nt < 4; nt++)
                Ps[(w * 16 + quad * 4 + r) * VLD + nt * 16 + l16] = f2bf(sc[nt][r]);
        }

        // O += P @ V : A-frag from Ps, B-frag from Vt
#pragma unroll
        for (int kstep = 0; kstep < 2; kstep++) {
            bf16x8 pf = *(const bf16x8*)&Ps[(w * 16 + l16) * VLD + kstep * 32 + quad * 8];
#pragma unroll
            for (int dt = 0; dt < 8; dt++) {
                bf16x8 vf = *(const bf16x8*)&Vt[(dt * 16 + l16) * VLD + kstep * 32 + quad * 8];
                ao[dt] = __builtin_amdgcn_mfma_f32_16x16x32_bf16(pf, vf, ao[dt], 0, 0, 0);
            }
        }
        __syncthreads();
    }

    // epilogue: Ctx[b][s][h*128+d] (bf16)
#pragma unroll
    for (int r = 0; r < 4; r++) {
        float inv = 1.0f / l_i[r];
        int qg = qw + quad * 4 + r;
        size_t rowbase = ((size_t)b * S_ + qg) * H_ + h * HD_;
#pragma unroll
        for (int dt = 0; dt < 8; dt++)
            Ctx[rowbase + dt * 16 + l16] = f2bf(ao[dt][r] * inv);
    }
}

extern "C" void kernel_launch(void* const* d_in, const int* in_sizes, int n_in,
                              void* d_out, int out_size, void* d_ws, size_t ws_size,
                              hipStream_t stream) {
    const float* x  = (const float*)d_in[0];
    const float* Wq = (const float*)d_in[1];
    const float* Wk = (const float*)d_in[2];
    const float* Wv = (const float*)d_in[3];
    const float* Wo = (const float*)d_in[4];
    float* out = (float*)d_out;

    const size_t MB = 1024 * 1024;
    char* ws = (char*)d_ws;
    u16* Xb    = (u16*)(ws);            // 16 MB : x as bf16 [4096,2048]
    u16* WqkvT = (u16*)(ws + 16 * MB);  // 24 MB : [6144,2048] (Wq^T;Wk^T;Wv^T)
    u16* WoT   = (u16*)(ws + 40 * MB);  //  8 MB : [2048,2048]
    u16* Qb    = (u16*)(ws + 48 * MB);  // 16 MB : [B,NH,S,HD]
    u16* Kbuf  = (u16*)(ws + 64 * MB);  // 16 MB
    u16* Vbuf  = (u16*)(ws + 80 * MB);  // 16 MB
    u16* Ctx   = (u16*)(ws + 96 * MB);  // 16 MB : [4096,2048] attn output

    cast_x_kernel<<<8192, 256, 0, stream>>>(x, Xb);
    transpose_cast_kernel<<<dim3(64, 64, 4), dim3(32, 8), 0, stream>>>(Wq, Wk, Wv, Wo, WqkvT, WoT);
    gemm_bt<0><<<dim3(48, 32), 256, 0, stream>>>(Xb, WqkvT, nullptr, Qb, Kbuf, Vbuf, 4096, 6144, 2048);
    flash_kernel<<<dim3(32, 16, 2), 256, 0, stream>>>(Qb, Kbuf, Vbuf, Ctx);
    gemm_bt<1><<<dim3(16, 32), 256, 0, stream>>>(Ctx, WoT, out, nullptr, nullptr, nullptr, 4096, 2048, 2048);
}

// Round 2
// 460.836 us; speedup vs baseline: 1.2728x; 1.2728x over previous
//
#include <hip/hip_runtime.h>
#include <stdint.h>

typedef unsigned short u16;
typedef __bf16 bf16x8 __attribute__((ext_vector_type(8)));
typedef float f32x4 __attribute__((ext_vector_type(4)));

#define B_ 2
#define S_ 2048
#define H_ 2048
#define NH_ 16
#define HD_ 128

__device__ __forceinline__ u16 f2bf(float f) {
    uint32_t u = __float_as_uint(f);
    u += 0x7fff + ((u >> 16) & 1);  // round-to-nearest-even
    return (u16)(u >> 16);
}

// async global->LDS, 16B per lane, LDS dest = wave-uniform base + lane*16
__device__ __forceinline__ void gl_lds16(const u16* g, u16* l) {
    __builtin_amdgcn_global_load_lds(
        (const __attribute__((address_space(1))) void*)g,
        (__attribute__((address_space(3))) void*)l, 16, 0, 0);
}

// ---------------- cast x (fp32 -> bf16) ----------------
__global__ __launch_bounds__(256) void cast_x_kernel(const float* __restrict__ x, u16* __restrict__ xb) {
    int i = (blockIdx.x * 256 + threadIdx.x) * 4;
    float4 v = *(const float4*)&x[i];
    ushort4 o;
    o.x = f2bf(v.x); o.y = f2bf(v.y); o.z = f2bf(v.z); o.w = f2bf(v.w);
    *(ushort4*)&xb[i] = o;
}

// ---------------- transpose + cast weights: Wt[n][k] = bf16(W[k][n]) ----------------
__global__ __launch_bounds__(256) void transpose_cast_kernel(
        const float* __restrict__ w0, const float* __restrict__ w1,
        const float* __restrict__ w2, const float* __restrict__ w3,
        u16* __restrict__ dqkv, u16* __restrict__ dwo) {
    int z = blockIdx.z;
    const float* src = (z == 0) ? w0 : (z == 1) ? w1 : (z == 2) ? w2 : w3;
    u16* dst = (z < 3) ? (dqkv + (size_t)z * H_ * H_) : dwo;
    __shared__ float tile[32][33];
    int n0 = blockIdx.x * 32, k0 = blockIdx.y * 32;
    int tx = threadIdx.x, ty = threadIdx.y;  // 32 x 8
#pragma unroll
    for (int i = 0; i < 4; i++)
        tile[ty + i * 8][tx] = src[(size_t)(k0 + ty + i * 8) * H_ + n0 + tx];
    __syncthreads();
#pragma unroll
    for (int i = 0; i < 4; i++)
        dst[(size_t)(n0 + ty + i * 8) * H_ + k0 + tx] = f2bf(tile[tx][ty + i * 8]);
}

// ---------------- GEMM: C[M,N] = A[M,K] @ Bt[N,K]^T  (bf16 in, fp32 acc) ----------------
// m97 structure: global_load_lds width-16 staging into unpadded XOR-swizzled LDS.
// LDS tile [128 rows][64 k] u16; 16B chunk c of row stored at position c ^ (row&7).
// MODE 0: scatter bf16 output into Q/K/V [B,NH,S,HD]; MODE 1: fp32 row-major [M,N]
template <int MODE>
__global__ __launch_bounds__(256, 2) void gemm_bt(
        const u16* __restrict__ A, const u16* __restrict__ Bt, float* __restrict__ Cout,
        u16* __restrict__ q, u16* __restrict__ k, u16* __restrict__ v,
        int M, int N, int K) {
    __shared__ u16 As[128 * 64];
    __shared__ u16 Bs[128 * 64];
    int tid = threadIdx.x;
    int w = tid >> 6, lane = tid & 63, quad = lane >> 4, l16 = lane & 15;
    int wm = w >> 1, wn = w & 1;
    int m0 = blockIdx.y * 128, n0 = blockIdx.x * 128;

    f32x4 acc[4][4];
#pragma unroll
    for (int mi = 0; mi < 4; mi++)
#pragma unroll
        for (int ni = 0; ni < 4; ni++)
            acc[mi][ni] = (f32x4){0.f, 0.f, 0.f, 0.f};

    for (int k0 = 0; k0 < K; k0 += 64) {
        const u16* ga = A + (size_t)m0 * K + k0;
        const u16* gb = Bt + (size_t)n0 * K + k0;
        // stage 128x64 u16 (16KB) each = 1024 chunks of 16B = 16 wave-calls, 4/wave
#pragma unroll
        for (int j = 0; j < 4; j++) {
            int base = (j * 4 + w) * 64;          // wave-uniform chunk base
            int p = base + lane;
            int row = p >> 3;
            int c = (p & 7) ^ (row & 7);          // gather the swizzled chunk
            gl_lds16(&ga[(size_t)row * K + c * 8], &As[base * 8]);
            gl_lds16(&gb[(size_t)row * K + c * 8], &Bs[base * 8]);
        }
        __syncthreads();
#pragma unroll
        for (int ks = 0; ks < 2; ks++) {
            bf16x8 af[4], bf[4];
#pragma unroll
            for (int mi = 0; mi < 4; mi++) {
                int row = wm * 64 + mi * 16 + l16;
                af[mi] = *(const bf16x8*)&As[row * 64 + (((ks * 4 + quad) ^ (row & 7)) * 8)];
            }
#pragma unroll
            for (int ni = 0; ni < 4; ni++) {
                int row = wn * 64 + ni * 16 + l16;
                bf[ni] = *(const bf16x8*)&Bs[row * 64 + (((ks * 4 + quad) ^ (row & 7)) * 8)];
            }
#pragma unroll
            for (int mi = 0; mi < 4; mi++)
#pragma unroll
                for (int ni = 0; ni < 4; ni++)
                    acc[mi][ni] = __builtin_amdgcn_mfma_f32_16x16x32_bf16(af[mi], bf[ni], acc[mi][ni], 0, 0, 0);
        }
        __syncthreads();
    }

    // epilogue: D layout col = lane&15, row = quad*4 + r (m89-verified)
#pragma unroll
    for (int mi = 0; mi < 4; mi++) {
#pragma unroll
        for (int ni = 0; ni < 4; ni++) {
            int ng = n0 + wn * 64 + ni * 16 + l16;
#pragma unroll
            for (int r = 0; r < 4; r++) {
                int mg = m0 + wm * 64 + mi * 16 + quad * 4 + r;
                float val = acc[mi][ni][r];
                if (MODE == 0) {
                    int which = ng >> 11;          // 0=Q 1=K 2=V
                    int rem = ng & 2047;
                    int h = rem >> 7, d = rem & 127;
                    int b = mg >> 11, s = mg & 2047;
                    u16* base = (which == 0) ? q : (which == 1) ? k : v;
                    base[((size_t)((b * NH_ + h) * S_ + s)) * HD_ + d] = f2bf(val);
                } else {
                    Cout[(size_t)mg * N + ng] = val;
                }
            }
        }
    }
}

// ---------------- causal flash attention (no-max softmax, swizzled LDS) ----------------
// grid: 1024 flat blocks; balanced qtile mapping so each CU's 4 resident blocks
// sum to a constant 66 kv-iterations. Block = 4 waves x 16 q-rows = 64 q-rows.
// LDS = 16K (Ks) + 16K (Vt) + 8K (Ps) = 40960 B -> 4 blocks/CU.
__global__ __launch_bounds__(256, 4) void flash_kernel(
        const u16* __restrict__ Q, const u16* __restrict__ Kb,
        const u16* __restrict__ Vb, u16* __restrict__ Ctx) {
    __shared__ u16 Ks[64 * 128];  // [kv][d], 16B chunk c at c ^ (kv&15)
    __shared__ u16 Vt[128 * 64];  // [d][kv], 16B chunk c at c ^ (d&7)
    __shared__ u16 Ps[64 * 64];   // [qrow][kv], 16B chunk c at c ^ (qrow&7)
    int tid = threadIdx.x;
    int w = tid >> 6, lane = tid & 63, quad = lane >> 4, l16 = lane & 15;

    // balanced mapping: id -> (qt, h, b); co-resident blocks {id, id+256, ...}
    // get qtiles {2g0, 2g0+1, 31-2g0, 30-2g0} -> 66 iterations per CU
    int id = blockIdx.x;
    int bh = id & 31;
    int b = bh >> 4, h = bh & 15;
    int G = id >> 5;
    int kk = G >> 3, g0 = G & 7;
    int t2 = g0 * 2 + (kk & 1);
    int qt = (kk < 2) ? t2 : (31 - t2);
    int q0 = qt * 64;

    size_t bhoff = ((size_t)b * NH_ + h) * S_ * HD_;
    const u16* Qp = Q + bhoff;
    const u16* Kp = Kb + bhoff;
    const u16* Vp = Vb + bhoff;
    int qw = q0 + w * 16;

    // Q fragments in registers (A-frag: A[m=lane&15][k=quad*8+j])
    bf16x8 qf[4];
#pragma unroll
    for (int ks = 0; ks < 4; ks++)
        qf[ks] = *(const bf16x8*)&Qp[(size_t)(qw + l16) * HD_ + ks * 32 + quad * 8];

    float l_part[4] = {0.f, 0.f, 0.f, 0.f};
    f32x4 ao[8];
#pragma unroll
    for (int dt = 0; dt < 8; dt++) ao[dt] = (f32x4){0.f, 0.f, 0.f, 0.f};

    const float sl2 = 0.08838834764831845f * 1.4426950408889634f;  // scale * log2(e)

    for (int kv0 = 0; kv0 <= q0; kv0 += 64) {
        bool diag = (kv0 == q0);
        // --- stage K tile [64][128] via global_load_lds (16 chunks/row, swizzled) ---
#pragma unroll
        for (int j = 0; j < 4; j++) {
            int base = (j * 4 + w) * 64;  // chunk base, wave-uniform
            int p = base + lane;
            int row = p >> 4;
            int c = (p & 15) ^ (row & 15);
            gl_lds16(&Kp[(size_t)(kv0 + row) * HD_ + c * 8], &Ks[base * 8]);
        }
        // --- stage V tile transposed into Vt[d][kv] (swizzled scalar writes) ---
#pragma unroll
        for (int i = 0; i < 4; i++) {
            int idx = tid + i * 256;
            int g = idx >> 6, s = idx & 63;
            int4 pv = *(const int4*)&Vp[(size_t)(kv0 + s) * HD_ + g * 8];
            const u16* pu = (const u16*)&pv;
#pragma unroll
            for (int j = 0; j < 8; j++) {
                int d = g * 8 + j;
                Vt[d * 64 + (((s >> 3) ^ (d & 7)) * 8) + (s & 7)] = pu[j];
            }
        }
        __syncthreads();

        // --- S = Q K^T : per wave 16 q-rows x 64 kv ---
        f32x4 sc[4];
#pragma unroll
        for (int nt = 0; nt < 4; nt++) {
            sc[nt] = (f32x4){0.f, 0.f, 0.f, 0.f};
            int row = nt * 16 + l16;
#pragma unroll
            for (int ks = 0; ks < 4; ks++) {
                bf16x8 kf = *(const bf16x8*)&Ks[row * 128 + (((ks * 4 + quad) ^ (row & 15)) * 8)];
                sc[nt] = __builtin_amdgcn_mfma_f32_16x16x32_bf16(qf[ks], kf, sc[nt], 0, 0, 0);
            }
        }

        // --- no-max softmax: p = exp2(s * scale * log2e); defer row-sum to end ---
#pragma unroll
        for (int r = 0; r < 4; r++) {
            int prow = w * 16 + quad * 4 + r;
            int qg = qw + quad * 4 + r;
            float psum = 0.f;
#pragma unroll
            for (int nt = 0; nt < 4; nt++) {
                float p = exp2f(sc[nt][r] * sl2);
                if (diag && (kv0 + nt * 16 + l16 > qg)) p = 0.f;
                sc[nt][r] = p;
                psum += p;
            }
            l_part[r] += psum;
            // P (C-layout) -> Ps LDS (per-wave region, swizzled)
#pragma unroll
            for (int nt = 0; nt < 4; nt++) {
                int col = nt * 16 + l16;
                Ps[prow * 64 + (((col >> 3) ^ (prow & 7)) * 8) + (col & 7)] = f2bf(sc[nt][r]);
            }
        }

        // --- O += P @ V ---
#pragma unroll
        for (int kstep = 0; kstep < 2; kstep++) {
            int prow = w * 16 + l16;
            bf16x8 pf = *(const bf16x8*)&Ps[prow * 64 + (((kstep * 4 + quad) ^ (prow & 7)) * 8)];
#pragma unroll
            for (int dt = 0; dt < 8; dt++) {
                int d = dt * 16 + l16;
                bf16x8 vf = *(const bf16x8*)&Vt[d * 64 + (((kstep * 4 + quad) ^ (d & 7)) * 8)];
                ao[dt] = __builtin_amdgcn_mfma_f32_16x16x32_bf16(pf, vf, ao[dt], 0, 0, 0);
            }
        }
        __syncthreads();
    }

    // --- epilogue: reduce l across l16 lanes once, then write Ctx bf16 ---
#pragma unroll
    for (int r = 0; r < 4; r++) {
        float l = l_part[r];
        l += __shfl_xor(l, 1);
        l += __shfl_xor(l, 2);
        l += __shfl_xor(l, 4);
        l += __shfl_xor(l, 8);
        float inv = 1.0f / l;
        int qg = qw + quad * 4 + r;
        size_t rowbase = ((size_t)b * S_ + qg) * H_ + h * HD_;
#pragma unroll
        for (int dt = 0; dt < 8; dt++)
            Ctx[rowbase + dt * 16 + l16] = f2bf(ao[dt][r] * inv);
    }
}

extern "C" void kernel_launch(void* const* d_in, const int* in_sizes, int n_in,
                              void* d_out, int out_size, void* d_ws, size_t ws_size,
                              hipStream_t stream) {
    const float* x  = (const float*)d_in[0];
    const float* Wq = (const float*)d_in[1];
    const float* Wk = (const float*)d_in[2];
    const float* Wv = (const float*)d_in[3];
    const float* Wo = (const float*)d_in[4];
    float* out = (float*)d_out;

    const size_t MB = 1024 * 1024;
    char* ws = (char*)d_ws;
    u16* Xb    = (u16*)(ws);            // 16 MB : x as bf16 [4096,2048]
    u16* WqkvT = (u16*)(ws + 16 * MB);  // 24 MB : [6144,2048] (Wq^T;Wk^T;Wv^T)
    u16* WoT   = (u16*)(ws + 40 * MB);  //  8 MB : [2048,2048]
    u16* Qb    = (u16*)(ws + 48 * MB);  // 16 MB : [B,NH,S,HD]
    u16* Kbuf  = (u16*)(ws + 64 * MB);  // 16 MB
    u16* Vbuf  = (u16*)(ws + 80 * MB);  // 16 MB
    u16* Ctx   = (u16*)(ws + 96 * MB);  // 16 MB : [4096,2048] attn output

    cast_x_kernel<<<8192, 256, 0, stream>>>(x, Xb);
    transpose_cast_kernel<<<dim3(64, 64, 4), dim3(32, 8), 0, stream>>>(Wq, Wk, Wv, Wo, WqkvT, WoT);
    gemm_bt<0><<<dim3(48, 32), 256, 0, stream>>>(Xb, WqkvT, nullptr, Qb, Kbuf, Vbuf, 4096, 6144, 2048);
    flash_kernel<<<1024, 256, 0, stream>>>(Qb, Kbuf, Vbuf, Ctx);
    gemm_bt<1><<<dim3(16, 32), 256, 0, stream>>>(Ctx, WoT, out, nullptr, nullptr, nullptr, 4096, 2048, 2048);
}

// Round 3
// 343.929 us; speedup vs baseline: 1.7054x; 1.3399x over previous
//
#include <hip/hip_runtime.h>
#include <stdint.h>

typedef unsigned short u16;
typedef __bf16 bf16x8 __attribute__((ext_vector_type(8)));
typedef float f32x4 __attribute__((ext_vector_type(4)));

#define B_ 2
#define S_ 2048
#define H_ 2048
#define NH_ 16
#define HD_ 128

__device__ __forceinline__ u16 f2bf(float f) {
    uint32_t u = __float_as_uint(f);
    u += 0x7fff + ((u >> 16) & 1);  // round-to-nearest-even
    return (u16)(u >> 16);
}

// async global->LDS, 16B per lane, LDS dest = wave-uniform base + lane*16
__device__ __forceinline__ void gl_lds16(const u16* g, u16* l) {
    __builtin_amdgcn_global_load_lds(
        (const __attribute__((address_space(1))) void*)g,
        (__attribute__((address_space(3))) void*)l, 16, 0, 0);
}

// ---------------- cast x (fp32 -> bf16) ----------------
__global__ __launch_bounds__(256) void cast_x_kernel(const float* __restrict__ x, u16* __restrict__ xb) {
    int i = (blockIdx.x * 256 + threadIdx.x) * 4;
    float4 v = *(const float4*)&x[i];
    ushort4 o;
    o.x = f2bf(v.x); o.y = f2bf(v.y); o.z = f2bf(v.z); o.w = f2bf(v.w);
    *(ushort4*)&xb[i] = o;
}

// ---------------- transpose + cast weights: Wt[n][k] = bf16(W[k][n]) ----------------
__global__ __launch_bounds__(256) void transpose_cast_kernel(
        const float* __restrict__ w0, const float* __restrict__ w1,
        const float* __restrict__ w2, const float* __restrict__ w3,
        u16* __restrict__ dqkv, u16* __restrict__ dwo) {
    int z = blockIdx.z;
    const float* src = (z == 0) ? w0 : (z == 1) ? w1 : (z == 2) ? w2 : w3;
    u16* dst = (z < 3) ? (dqkv + (size_t)z * H_ * H_) : dwo;
    __shared__ float tile[32][33];
    int n0 = blockIdx.x * 32, k0 = blockIdx.y * 32;
    int tx = threadIdx.x, ty = threadIdx.y;  // 32 x 8
#pragma unroll
    for (int i = 0; i < 4; i++)
        tile[ty + i * 8][tx] = src[(size_t)(k0 + ty + i * 8) * H_ + n0 + tx];
    __syncthreads();
#pragma unroll
    for (int i = 0; i < 4; i++)
        dst[(size_t)(n0 + ty + i * 8) * H_ + k0 + tx] = f2bf(tile[tx][ty + i * 8]);
}

// ---------------- V transpose: Vbuf[b,h,s,d] -> VT[b,h,d,s] (bf16) ----------------
__global__ __launch_bounds__(256) void vtrans_kernel(const u16* __restrict__ V, u16* __restrict__ VT) {
    __shared__ u16 t[64 * 72];
    int bh = blockIdx.z;
    int s0 = blockIdx.x * 64, d0 = blockIdx.y * 64;
    const u16* src = V + (size_t)bh * S_ * HD_;
    u16* dst = VT + (size_t)bh * S_ * HD_;
    int tid = threadIdx.x;
#pragma unroll
    for (int i = 0; i < 2; i++) {
        int p = i * 256 + tid, r = p >> 3, c = p & 7;
        *(int4*)&t[r * 72 + c * 8] = *(const int4*)&src[(size_t)(s0 + r) * HD_ + d0 + c * 8];
    }
    __syncthreads();
#pragma unroll
    for (int i = 0; i < 2; i++) {
        int p = i * 256 + tid, rd = p >> 3, c = p & 7;
        u16 tmp[8];
#pragma unroll
        for (int j = 0; j < 8; j++) tmp[j] = t[(c * 8 + j) * 72 + rd];
        *(int4*)&dst[(size_t)(d0 + rd) * S_ + s0 + c * 8] = *(int4*)tmp;
    }
}

// ---------------- GEMM: C[M,N] = A[M,K] @ Bt[N,K]^T  (bf16 in, fp32 acc) ----------------
template <int MODE>
__global__ __launch_bounds__(256, 2) void gemm_bt(
        const u16* __restrict__ A, const u16* __restrict__ Bt, float* __restrict__ Cout,
        u16* __restrict__ q, u16* __restrict__ k, u16* __restrict__ v,
        int M, int N, int K) {
    __shared__ u16 As[128 * 64];
    __shared__ u16 Bs[128 * 64];
    int tid = threadIdx.x;
    int w = tid >> 6, lane = tid & 63, quad = lane >> 4, l16 = lane & 15;
    int wm = w >> 1, wn = w & 1;
    int m0 = blockIdx.y * 128, n0 = blockIdx.x * 128;

    f32x4 acc[4][4];
#pragma unroll
    for (int mi = 0; mi < 4; mi++)
#pragma unroll
        for (int ni = 0; ni < 4; ni++)
            acc[mi][ni] = (f32x4){0.f, 0.f, 0.f, 0.f};

    for (int k0 = 0; k0 < K; k0 += 64) {
        const u16* ga = A + (size_t)m0 * K + k0;
        const u16* gb = Bt + (size_t)n0 * K + k0;
#pragma unroll
        for (int j = 0; j < 4; j++) {
            int base = (j * 4 + w) * 64;
            int p = base + lane;
            int row = p >> 3;
            int c = (p & 7) ^ (row & 7);
            gl_lds16(&ga[(size_t)row * K + c * 8], &As[base * 8]);
            gl_lds16(&gb[(size_t)row * K + c * 8], &Bs[base * 8]);
        }
        __syncthreads();
#pragma unroll
        for (int ks = 0; ks < 2; ks++) {
            bf16x8 af[4], bf[4];
#pragma unroll
            for (int mi = 0; mi < 4; mi++) {
                int row = wm * 64 + mi * 16 + l16;
                af[mi] = *(const bf16x8*)&As[row * 64 + (((ks * 4 + quad) ^ (row & 7)) * 8)];
            }
#pragma unroll
            for (int ni = 0; ni < 4; ni++) {
                int row = wn * 64 + ni * 16 + l16;
                bf[ni] = *(const bf16x8*)&Bs[row * 64 + (((ks * 4 + quad) ^ (row & 7)) * 8)];
            }
#pragma unroll
            for (int mi = 0; mi < 4; mi++)
#pragma unroll
                for (int ni = 0; ni < 4; ni++)
                    acc[mi][ni] = __builtin_amdgcn_mfma_f32_16x16x32_bf16(af[mi], bf[ni], acc[mi][ni], 0, 0, 0);
        }
        __syncthreads();
    }

#pragma unroll
    for (int mi = 0; mi < 4; mi++) {
#pragma unroll
        for (int ni = 0; ni < 4; ni++) {
            int ng = n0 + wn * 64 + ni * 16 + l16;
#pragma unroll
            for (int r = 0; r < 4; r++) {
                int mg = m0 + wm * 64 + mi * 16 + quad * 4 + r;
                float val = acc[mi][ni][r];
                if (MODE == 0) {
                    int which = ng >> 11;          // 0=Q 1=K 2=V
                    int rem = ng & 2047;
                    int h = rem >> 7, d = rem & 127;
                    int b = mg >> 11, s = mg & 2047;
                    u16* base = (which == 0) ? q : (which == 1) ? k : v;
                    base[((size_t)((b * NH_ + h) * S_ + s)) * HD_ + d] = f2bf(val);
                } else {
                    Cout[(size_t)mg * N + ng] = val;
                }
            }
        }
    }
}

// ---------------- causal flash attention: paired q-tiles, DMA-staged, K double-buffered ----------------
// 512 blocks; block (b,h,pair) processes q-tiles qt=pair and qt=31-pair -> exactly 33 kv-iters.
// LDS: Ks 2x16KB (dbuf DMA) + Vs 16KB (DMA, from pre-transposed VT) + Ps 8KB = 56KB -> 2 blocks/CU.
__global__ __launch_bounds__(256, 2) void flash_kernel(
        const u16* __restrict__ Q, const u16* __restrict__ Kb,
        const u16* __restrict__ VT, u16* __restrict__ Ctx) {
    __shared__ u16 Ks[2][64 * 128];  // [kv][d], chunk c at c ^ (kv&15)
    __shared__ u16 Vs[128 * 64];     // [d][kv], chunk c at c ^ (d&7)
    __shared__ u16 Ps[64 * 64];      // [qrow][kv], chunk c at c ^ (qrow&7)
    int tid = threadIdx.x;
    int w = tid >> 6, lane = tid & 63, quad = lane >> 4, l16 = lane & 15;

    int id = blockIdx.x;
    int bh = id & 31;
    int b = bh >> 4, h = bh & 15;
    int pair = id >> 5;              // 0..15
    int qts = pair, qtl = 31 - pair;
    int n0 = qts + 1;                // kv-tiles in segment 0; total always 33

    size_t bhoff = ((size_t)b * NH_ + h) * S_ * HD_;
    const u16* Qp = Q + bhoff;
    const u16* Kp = Kb + bhoff;
    const u16* Vp = VT + bhoff;      // [d][s]: d*2048 + s

    // ---- staging helpers (DMA; LDS base wave-uniform) ----
    auto stageK = [&](int t, int buf) {
        int kv0 = ((t >= n0) ? (t - n0) : t) * 64;
#pragma unroll
        for (int j = 0; j < 4; j++) {
            int base = (j * 4 + w) * 64;
            int p = base + lane;
            int row = p >> 4;
            int c = (p & 15) ^ (row & 15);
            gl_lds16(&Kp[(size_t)(kv0 + row) * HD_ + c * 8], &Ks[buf][base * 8]);
        }
    };
    auto stageV = [&](int t) {
        int kv0 = ((t >= n0) ? (t - n0) : t) * 64;
#pragma unroll
        for (int j = 0; j < 4; j++) {
            int base = (j * 4 + w) * 64;
            int p = base + lane;
            int row = p >> 3;
            int c = (p & 7) ^ (row & 7);
            gl_lds16(&Vp[(size_t)row * S_ + kv0 + c * 8], &Vs[base * 8]);
        }
    };

    int q0 = qts * 64, qw = q0 + w * 16;
    bf16x8 qf[4];
#pragma unroll
    for (int ks = 0; ks < 4; ks++)
        qf[ks] = *(const bf16x8*)&Qp[(size_t)(qw + l16) * HD_ + ks * 32 + quad * 8];

    float l_part[4] = {0.f, 0.f, 0.f, 0.f};
    f32x4 ao[8];
#pragma unroll
    for (int dt = 0; dt < 8; dt++) ao[dt] = (f32x4){0.f, 0.f, 0.f, 0.f};

    const float sl2 = 0.08838834764831845f * 1.4426950408889634f;  // scale * log2(e)

    auto epilogue = [&]() {
#pragma unroll
        for (int r = 0; r < 4; r++) {
            float l = l_part[r];
            l += __shfl_xor(l, 1);
            l += __shfl_xor(l, 2);
            l += __shfl_xor(l, 4);
            l += __shfl_xor(l, 8);
            float inv = 1.0f / l;
            int qg = qw + quad * 4 + r;
            size_t rowbase = ((size_t)b * S_ + qg) * H_ + h * HD_;
#pragma unroll
            for (int dt = 0; dt < 8; dt++)
                Ctx[rowbase + dt * 16 + l16] = f2bf(ao[dt][r] * inv);
        }
    };

    stageK(0, 0);  // prologue; drained at first barrier

    for (int t = 0; t < 33; t++) {
        __syncthreads();                 // drains K(t) DMA; Vs/Ks[alt] readers done
        if (t + 1 < 33) stageK(t + 1, (t + 1) & 1);
        stageV(t);
        if (t == n0) {                   // segment switch: finish qts, start qtl
            epilogue();
            q0 = qtl * 64; qw = q0 + w * 16;
#pragma unroll
            for (int ks = 0; ks < 4; ks++)
                qf[ks] = *(const bf16x8*)&Qp[(size_t)(qw + l16) * HD_ + ks * 32 + quad * 8];
#pragma unroll
            for (int r = 0; r < 4; r++) l_part[r] = 0.f;
#pragma unroll
            for (int dt = 0; dt < 8; dt++) ao[dt] = (f32x4){0.f, 0.f, 0.f, 0.f};
        }
        int kv0 = ((t >= n0) ? (t - n0) : t) * 64;
        bool diag = (kv0 == q0);
        int buf = t & 1;

        // --- S = Q K^T ---
        f32x4 sc[4];
#pragma unroll
        for (int nt = 0; nt < 4; nt++) {
            sc[nt] = (f32x4){0.f, 0.f, 0.f, 0.f};
            int row = nt * 16 + l16;
#pragma unroll
            for (int ks = 0; ks < 4; ks++) {
                bf16x8 kf = *(const bf16x8*)&Ks[buf][row * 128 + (((ks * 4 + quad) ^ (row & 15)) * 8)];
                sc[nt] = __builtin_amdgcn_mfma_f32_16x16x32_bf16(qf[ks], kf, sc[nt], 0, 0, 0);
            }
        }

        // --- no-max softmax + P -> LDS ---
#pragma unroll
        for (int r = 0; r < 4; r++) {
            int prow = w * 16 + quad * 4 + r;
            int qg = qw + quad * 4 + r;
            float psum = 0.f;
#pragma unroll
            for (int nt = 0; nt < 4; nt++) {
                float p = exp2f(sc[nt][r] * sl2);
                if (diag && (kv0 + nt * 16 + l16 > qg)) p = 0.f;
                sc[nt][r] = p;
                psum += p;
            }
            l_part[r] += psum;
#pragma unroll
            for (int nt = 0; nt < 4; nt++) {
                int col = nt * 16 + l16;
                Ps[prow * 64 + (((col >> 3) ^ (prow & 7)) * 8) + (col & 7)] = f2bf(sc[nt][r]);
            }
        }

        __syncthreads();                 // drains V(t) DMA (hidden under QK+softmax)

        // --- O += P @ V ---
#pragma unroll
        for (int kstep = 0; kstep < 2; kstep++) {
            int prow = w * 16 + l16;
            bf16x8 pf = *(const bf16x8*)&Ps[prow * 64 + (((kstep * 4 + quad) ^ (prow & 7)) * 8)];
#pragma unroll
            for (int dt = 0; dt < 8; dt++) {
                int d = dt * 16 + l16;
                bf16x8 vf = *(const bf16x8*)&Vs[d * 64 + (((kstep * 4 + quad) ^ (d & 7)) * 8)];
                ao[dt] = __builtin_amdgcn_mfma_f32_16x16x32_bf16(pf, vf, ao[dt], 0, 0, 0);
            }
        }
    }
    epilogue();
}

extern "C" void kernel_launch(void* const* d_in, const int* in_sizes, int n_in,
                              void* d_out, int out_size, void* d_ws, size_t ws_size,
                              hipStream_t stream) {
    const float* x  = (const float*)d_in[0];
    const float* Wq = (const float*)d_in[1];
    const float* Wk = (const float*)d_in[2];
    const float* Wv = (const float*)d_in[3];
    const float* Wo = (const float*)d_in[4];
    float* out = (float*)d_out;

    const size_t MB = 1024 * 1024;
    char* ws = (char*)d_ws;
    u16* Xb    = (u16*)(ws);            // 16 MB : x bf16 (reused as VT after gemm0)
    u16* WqkvT = (u16*)(ws + 16 * MB);  // 24 MB
    u16* WoT   = (u16*)(ws + 40 * MB);  //  8 MB
    u16* Qb    = (u16*)(ws + 48 * MB);  // 16 MB
    u16* Kbuf  = (u16*)(ws + 64 * MB);  // 16 MB
    u16* Vbuf  = (u16*)(ws + 80 * MB);  // 16 MB
    u16* Ctx   = (u16*)(ws + 96 * MB);  // 16 MB
    u16* VT    = Xb;                    // alias: Xb dead after gemm0

    cast_x_kernel<<<8192, 256, 0, stream>>>(x, Xb);
    transpose_cast_kernel<<<dim3(64, 64, 4), dim3(32, 8), 0, stream>>>(Wq, Wk, Wv, Wo, WqkvT, WoT);
    gemm_bt<0><<<dim3(48, 32), 256, 0, stream>>>(Xb, WqkvT, nullptr, Qb, Kbuf, Vbuf, 4096, 6144, 2048);
    vtrans_kernel<<<dim3(32, 2, 32), 256, 0, stream>>>(Vbuf, VT);
    flash_kernel<<<512, 256, 0, stream>>>(Qb, Kbuf, VT, Ctx);
    gemm_bt<1><<<dim3(16, 32), 256, 0, stream>>>(Ctx, WoT, out, nullptr, nullptr, nullptr, 4096, 2048, 2048);
}